// Round 3
// baseline (195.162 us; speedup 1.0000x reference)
//
#include <hip/hip_runtime.h>

#define HW   4096
#define HIMG 64
#define WIMG 64
#define CC   256
#define CR   32
#define B_   8

typedef __attribute__((ext_vector_type(8))) short bf16x8;
typedef __attribute__((ext_vector_type(4))) float f32x4;

__device__ inline unsigned short f2bf(float f) {
    union { float f; unsigned u; } v; v.f = f;
    return (unsigned short)((v.u + 0x8000u) >> 16);
}
__device__ inline float bf2f(unsigned short h) {
    union { unsigned u; float f; } v; v.u = ((unsigned)h) << 16; return v.f;
}
__device__ inline unsigned pack2(float a, float b) {
    return (unsigned)f2bf(a) | ((unsigned)f2bf(b) << 16);
}

// ---------------------------------------------------------------------------
// K1: weights -> bf16, concat [Wq;Wk;Wv] into Wb[320][256]; biases into bb.
// ---------------------------------------------------------------------------
__global__ __launch_bounds__(256) void wconv(
    const float* __restrict__ Wq, const float* __restrict__ bq,
    const float* __restrict__ Wk, const float* __restrict__ bk,
    const float* __restrict__ Wv, const float* __restrict__ bv,
    unsigned short* __restrict__ Wb, float* __restrict__ bb)
{
    const int o = blockIdx.x;   // 0..319
    const float* src; const float* bsrc; int orel;
    if (o < 32)      { src = Wq; bsrc = bq; orel = o;      }
    else if (o < 64) { src = Wk; bsrc = bk; orel = o - 32; }
    else             { src = Wv; bsrc = bv; orel = o - 64; }
    Wb[o * CC + threadIdx.x] = f2bf(src[orel * CC + threadIdx.x]);
    if (threadIdx.x == 0) bb[o] = bsrc[orel];
}

// ---------------------------------------------------------------------------
// K2: FULLY FUSED. One block per (h-row, batch): 512 blocks x 512 threads.
// Phase 1: proj GEMM M=320 x N=192px (rows h-1..h+1, 3x redundant halo
//          compute) x K=256, cloned from the proven R0 tile structure.
//          Results go straight to LDS (q/k fp32, v bf16) -- q/k/vv/aw never
//          touch HBM.
// Phase 2: energies -> softmax -> stencil-apply + residual, all from LDS.
// LDS: union{ phase1 121KB | phase2 149.8KB } -> 1 block/CU, 8 waves.
// h-swizzle: XCD i owns h in [8i, 8i+8) -> halo x reads are L2 hits.
// ---------------------------------------------------------------------------
__global__ __launch_bounds__(512) void fused(
    const unsigned short* __restrict__ Wb, const float* __restrict__ bb,
    const float* __restrict__ x, const float* __restrict__ gamma,
    float* __restrict__ out)
{
    struct P1 {
        unsigned short As[320 * 72];   // 46080 B
        float          xt[64 * 196];   // 50176 B
        unsigned short Bs[192 * 64];   // 24576 B
    };
    struct P2 {
        unsigned short vL[3][256][72]; // 110592 B  [row][ch][4z|64px|4z]
        float          kL[3][64][33];  //  25344 B  [row][px][ch]
        float          qL[64][33];     //   8448 B  [px][ch]
        float          es[64][9];      //   2304 B
        float          aws[64][12];    //   3072 B
    };
    __shared__ union SM { P1 p1; P2 p2; } sm;   // 149760 B

    const int t    = threadIdx.x;
    const int hx   = blockIdx.x;                  // 0..63
    const int h    = ((hx & 7) << 3) | (hx >> 3); // XCD-contiguous h ranges
    const int b    = blockIdx.y;
    const int lane = t & 63, wv = t >> 6;
    const int m16  = lane & 15, quad = lane >> 4;
    const int wm   = wv & 3, wn = wv >> 2;        // 4 M-waves x 2 N-waves

    f32x4 acc[5][6];
    #pragma unroll
    for (int i = 0; i < 5; ++i)
        #pragma unroll
        for (int n = 0; n < 6; ++n)
            acc[i][n] = (f32x4){0.f, 0.f, 0.f, 0.f};

    // ================= phase 1: projection GEMM =================
    for (int kc = 0; kc < 4; ++kc) {
        const int k0 = kc * 64;
        if (kc) __syncthreads();

        // stage A: 320 rows x 64 ch bf16 (L2-resident Wb), 2560 uint4
        #pragma unroll
        for (int i = 0; i < 5; ++i) {
            int idx = t + 512 * i;
            int row = idx >> 3, s8 = idx & 7;
            *(uint4*)&sm.p1.As[row * 72 + s8 * 8] =
                *(const uint4*)&Wb[row * CC + k0 + s8 * 8];
        }
        // stage x chunk fp32: 64 ch x 192 px (rows h-1..h+1), 3072 float4
        #pragma unroll
        for (int i = 0; i < 6; ++i) {
            int idx = t + 512 * i;          // 0..3071
            int c = idx / 48, f4 = idx % 48;
            int p4 = f4 * 4;                // 0..188 (each float4 within one row)
            int ri = p4 >> 6;
            int hh = h + ri - 1;
            float4 vx = make_float4(0.f, 0.f, 0.f, 0.f);
            if (hh >= 0 && hh < HIMG)
                vx = *(const float4*)&x[((size_t)b * CC + k0 + c) * HW
                                         + hh * WIMG + (p4 & 63)];
            *(float4*)&sm.p1.xt[c * 196 + p4] = vx;
        }
        __syncthreads();

        // transpose+convert into Bs: 12 tasks of (64 px x 16 ch) over 8 waves
        #pragma unroll
        for (int rep = 0; rep < 2; ++rep) {
            int tk = wv + 8 * rep;
            if (tk < 12) {
                int px = (tk % 3) * 64 + lane;
                int c0 = (tk / 3) * 16;
                float f[16];
                #pragma unroll
                for (int j = 0; j < 16; ++j)
                    f[j] = sm.p1.xt[(c0 + j) * 196 + px];
                uint4 w0, w1;
                w0.x = pack2(f[0],  f[1]);  w0.y = pack2(f[2],  f[3]);
                w0.z = pack2(f[4],  f[5]);  w0.w = pack2(f[6],  f[7]);
                w1.x = pack2(f[8],  f[9]);  w1.y = pack2(f[10], f[11]);
                w1.z = pack2(f[12], f[13]); w1.w = pack2(f[14], f[15]);
                const int lg0 = c0 >> 3, sw = px & 7;
                *(uint4*)&sm.p1.Bs[px * 64 + ((lg0       ^ sw) * 8)] = w0;
                *(uint4*)&sm.p1.Bs[px * 64 + (((lg0 + 1) ^ sw) * 8)] = w1;
            }
        }
        __syncthreads();

        #pragma unroll
        for (int ks = 0; ks < 2; ++ks) {
            bf16x8 af[5], bf[6];
            #pragma unroll
            for (int i = 0; i < 5; ++i)
                af[i] = *(const bf16x8*)&sm.p1.As[((wm * 5 + i) * 16 + m16) * 72
                                                   + ks * 32 + quad * 8];
            #pragma unroll
            for (int n = 0; n < 6; ++n) {
                int px = wn * 96 + n * 16 + m16;
                int lg = ks * 4 + quad;
                bf[n] = *(const bf16x8*)&sm.p1.Bs[px * 64 + ((lg ^ (px & 7)) * 8)];
            }
            #pragma unroll
            for (int i = 0; i < 5; ++i)
                #pragma unroll
                for (int n = 0; n < 6; ++n)
                    acc[i][n] = __builtin_amdgcn_mfma_f32_16x16x32_bf16(
                        af[i], bf[n], acc[i][n], 0, 0, 0);
        }
    }
    __syncthreads();   // phase-1 LDS dead; union flips to phase-2 layout

    // ================= epilogue: acc -> qL / kL / vL =================
    #pragma unroll
    for (int i = 0; i < 5; ++i) {
        const int ob = wm * 80 + i * 16;
        #pragma unroll
        for (int r = 0; r < 4; ++r) {
            const int m = ob + quad * 4 + r;   // out-channel 0..319
            const float bias = bb[m];
            #pragma unroll
            for (int n = 0; n < 6; ++n) {
                int px = wn * 96 + n * 16 + m16;   // 0..191
                int ri = px >> 6, ww = px & 63;
                float val = acc[i][n][r] + bias;
                if (m < CR) {
                    if (ri == 1) sm.p2.qL[ww][m] = val;
                } else if (m < 2 * CR) {
                    sm.p2.kL[ri][ww][m - CR] = val;   // OOB rows masked at use
                } else {
                    bool rv = (unsigned)(h + ri - 1) < (unsigned)HIMG;
                    sm.p2.vL[ri][m - 2 * CR][4 + ww] =
                        rv ? f2bf(val) : (unsigned short)0;
                }
            }
        }
    }
    // zero the 4-px pads on both ends of every vL row
    for (int p = t; p < 768; p += 512) {
        int r = p >> 8, c = p & 255;
        *(ushort4*)&sm.p2.vL[r][c][0]  = make_ushort4(0, 0, 0, 0);
        *(ushort4*)&sm.p2.vL[r][c][68] = make_ushort4(0, 0, 0, 0);
    }
    __syncthreads();

    // ================= energies =================
    for (int id = t; id < 576; id += 512) {
        int px = id / 9, kk = id - px * 9;
        int di = kk / 3, dj = kk - di * 3;
        int hh = h + di - 1, ww = px + dj - 1;
        float e = 0.f;
        if (hh >= 0 && hh < HIMG && ww >= 0 && ww < WIMG) {
            float s = 0.f;
            #pragma unroll
            for (int c = 0; c < CR; ++c)
                s = fmaf(sm.p2.qL[px][c], sm.p2.kL[di][ww][c], s);
            e = s;
        }
        sm.p2.es[px][kk] = e;
    }
    __syncthreads();

    // ================= softmax =================
    if (t < 64) {
        float m = sm.p2.es[t][0];
        #pragma unroll
        for (int kk = 1; kk < 9; ++kk) m = fmaxf(m, sm.p2.es[t][kk]);
        float ex[9]; float ssum = 0.f;
        #pragma unroll
        for (int kk = 0; kk < 9; ++kk) {
            ex[kk] = __expf(sm.p2.es[t][kk] - m);
            ssum += ex[kk];
        }
        float inv = 1.f / ssum;
        #pragma unroll
        for (int kk = 0; kk < 9; ++kk) sm.p2.aws[t][kk] = ex[kk] * inv;
    }
    __syncthreads();

    // ================= apply + residual =================
    {
        const int px0 = (t & 15) * 4;
        const int cl  = t >> 4;                 // 0..31
        const float g = gamma[0];
        float w[4][9];
        #pragma unroll
        for (int i = 0; i < 4; ++i)
            #pragma unroll
            for (int kk = 0; kk < 9; ++kk) w[i][kk] = sm.p2.aws[px0 + i][kk];

        #pragma unroll
        for (int ci = 0; ci < 8; ++ci) {
            int c = cl + 32 * ci;
            float a0 = 0.f, a1 = 0.f, a2 = 0.f, a3 = 0.f;
            #pragma unroll
            for (int r = 0; r < 3; ++r) {
                const unsigned short* row = &sm.p2.vL[r][c][0];
                ushort4 uc = *(const ushort4*)&row[4 + px0];
                float c0 = bf2f(uc.x), c1 = bf2f(uc.y);
                float c2 = bf2f(uc.z), c3 = bf2f(uc.w);
                float lft = bf2f(row[3 + px0]);
                float rgt = bf2f(row[8 + px0]);
                int r3 = r * 3;
                a0 = fmaf(w[0][r3], lft, fmaf(w[0][r3+1], c0, fmaf(w[0][r3+2], c1, a0)));
                a1 = fmaf(w[1][r3], c0,  fmaf(w[1][r3+1], c1, fmaf(w[1][r3+2], c2, a1)));
                a2 = fmaf(w[2][r3], c1,  fmaf(w[2][r3+1], c2, fmaf(w[2][r3+2], c3, a2)));
                a3 = fmaf(w[3][r3], c2,  fmaf(w[3][r3+1], c3, fmaf(w[3][r3+2], rgt, a3)));
            }
            size_t base = ((size_t)b * CC + c) * HW + h * WIMG + px0;
            float4 xa = *(const float4*)&x[base];
            float4 o;
            o.x = fmaf(g, a0, xa.x); o.y = fmaf(g, a1, xa.y);
            o.z = fmaf(g, a2, xa.z); o.w = fmaf(g, a3, xa.w);
            *(float4*)&out[base] = o;
        }
    }
}

extern "C" void kernel_launch(void* const* d_in, const int* in_sizes, int n_in,
                              void* d_out, int out_size, void* d_ws, size_t ws_size,
                              hipStream_t stream)
{
    const float* x     = (const float*)d_in[0];
    const float* Wq    = (const float*)d_in[1];
    const float* bq    = (const float*)d_in[2];
    const float* Wk    = (const float*)d_in[3];
    const float* bk    = (const float*)d_in[4];
    const float* Wv    = (const float*)d_in[5];
    const float* bv    = (const float*)d_in[6];
    const float* gamma = (const float*)d_in[7];
    float* out = (float*)d_out;

    unsigned short* Wb = (unsigned short*)d_ws;        // 160 KB
    float* bb = (float*)(Wb + 320 * CC);               // 1.25 KB

    wconv<<<dim3(320), 256, 0, stream>>>(Wq, bq, Wk, bk, Wv, bv, Wb, bb);
    fused<<<dim3(HIMG, B_), 512, 0, stream>>>(Wb, bb, x, gamma, out);
}

// Round 4
// 186.808 us; speedup vs baseline: 1.0447x; 1.0447x over previous
//
#include <hip/hip_runtime.h>

#define HW   4096
#define HIMG 64
#define WIMG 64
#define CC   256
#define CR   32
#define B_   8

typedef __attribute__((ext_vector_type(8))) short bf16x8;
typedef __attribute__((ext_vector_type(4))) float f32x4;

__device__ inline unsigned short f2bf(float f) {
    union { float f; unsigned u; } v; v.f = f;
    return (unsigned short)((v.u + 0x8000u) >> 16);
}
__device__ inline float bf2f(unsigned short h) {
    union { unsigned u; float f; } v; v.u = ((unsigned)h) << 16; return v.f;
}
__device__ inline unsigned pack2(float a, float b) {
    return (unsigned)f2bf(a) | ((unsigned)f2bf(b) << 16);
}

// ---------------------------------------------------------------------------
// K1: weights -> bf16, concat [Wq;Wk;Wv] into Wb[320][256]; biases into bb.
// ---------------------------------------------------------------------------
__global__ __launch_bounds__(256) void wconv(
    const float* __restrict__ Wq, const float* __restrict__ bq,
    const float* __restrict__ Wk, const float* __restrict__ bk,
    const float* __restrict__ Wv, const float* __restrict__ bv,
    unsigned short* __restrict__ Wb, float* __restrict__ bb)
{
    const int o = blockIdx.x;   // 0..319
    const float* src; const float* bsrc; int orel;
    if (o < 32)      { src = Wq; bsrc = bq; orel = o;      }
    else if (o < 64) { src = Wk; bsrc = bk; orel = o - 32; }
    else             { src = Wv; bsrc = bv; orel = o - 64; }
    Wb[o * CC + threadIdx.x] = f2bf(src[orel * CC + threadIdx.x]);
    if (threadIdx.x == 0) bb[o] = bsrc[orel];
}

// ---------------------------------------------------------------------------
// K2: FULLY FUSED, v2. One block per (h-row, batch): 512 blocks x 1024 thr.
// R3 counters said: Occupancy 21.8% (8 waves/CU), 17.2M LDS bank conflicts.
// Fixes: (1) 1024 threads -> 16 waves/CU, every phase 2x parallel;
//        (2) vL row stride 72 -> 74 shorts (37 dwords, ODD) -> apply-phase
//            reads and epilogue writes drop from 4-way to <=2-way conflicts;
//        (3) residual-x prefetch overlaps HBM latency with energies/softmax.
// GEMM tiling: 4 M-waves (80 rows) x 4 N-waves (48 px), acc[5][3]/wave.
// Arithmetic identical to R3 (which passed, absmax 0.015625).
// ---------------------------------------------------------------------------
__global__ __launch_bounds__(1024) void fused(
    const unsigned short* __restrict__ Wb, const float* __restrict__ bb,
    const float* __restrict__ x, const float* __restrict__ gamma,
    float* __restrict__ out)
{
    struct P1 {
        unsigned short As[320 * 72];   // 46080 B
        float          xt[64 * 196];   // 50176 B
        unsigned short Bs[192 * 64];   // 24576 B
    };
    struct P2 {
        unsigned short vL[3][256][74]; // 113664 B  [row][ch][4z|64px|4z|2]
        float          kL[3][64][33];  //  25344 B  [row][px][ch]
        float          qL[64][33];     //   8448 B  [px][ch]
        float          es[64][9];      //   2304 B
        float          aws[64][12];    //   3072 B
    };
    __shared__ union SM { P1 p1; P2 p2; } sm;   // 152832 B

    const int t    = threadIdx.x;
    const int hx   = blockIdx.x;                  // 0..63
    const int h    = ((hx & 7) << 3) | (hx >> 3); // XCD-contiguous h ranges
    const int b    = blockIdx.y;
    const int lane = t & 63, wv = t >> 6;         // 16 waves
    const int m16  = lane & 15, quad = lane >> 4;
    const int wm   = wv & 3, wn = wv >> 2;        // 4 M-waves x 4 N-waves

    f32x4 acc[5][3];
    #pragma unroll
    for (int i = 0; i < 5; ++i)
        #pragma unroll
        for (int n = 0; n < 3; ++n)
            acc[i][n] = (f32x4){0.f, 0.f, 0.f, 0.f};

    // ================= phase 1: projection GEMM =================
    for (int kc = 0; kc < 4; ++kc) {
        const int k0 = kc * 64;
        if (kc) __syncthreads();

        // stage A: 320 rows x 64 ch bf16 (L2-resident Wb), 2560 uint4
        #pragma unroll
        for (int i = 0; i < 3; ++i) {
            int idx = t + 1024 * i;
            if (idx < 2560) {
                int row = idx >> 3, s8 = idx & 7;
                *(uint4*)&sm.p1.As[row * 72 + s8 * 8] =
                    *(const uint4*)&Wb[row * CC + k0 + s8 * 8];
            }
        }
        // stage x chunk fp32: 64 ch x 192 px (rows h-1..h+1), 3072 float4
        #pragma unroll
        for (int i = 0; i < 3; ++i) {
            int idx = t + 1024 * i;         // 0..3071
            int c = idx / 48, f4 = idx % 48;
            int p4 = f4 * 4;                // 0..188
            int ri = p4 >> 6;
            int hh = h + ri - 1;
            float4 vx = make_float4(0.f, 0.f, 0.f, 0.f);
            if (hh >= 0 && hh < HIMG)
                vx = *(const float4*)&x[((size_t)b * CC + k0 + c) * HW
                                         + hh * WIMG + (p4 & 63)];
            *(float4*)&sm.p1.xt[c * 196 + p4] = vx;
        }
        __syncthreads();

        // transpose+convert into Bs: 24 tasks of (64 px x 8 ch) over 16 waves
        #pragma unroll
        for (int rep = 0; rep < 2; ++rep) {
            int tk = wv + 16 * rep;
            if (tk < 24) {
                int px = (tk % 3) * 64 + lane;
                int c0 = (tk / 3) * 8;
                float f[8];
                #pragma unroll
                for (int j = 0; j < 8; ++j)
                    f[j] = sm.p1.xt[(c0 + j) * 196 + px];
                uint4 w0;
                w0.x = pack2(f[0], f[1]); w0.y = pack2(f[2], f[3]);
                w0.z = pack2(f[4], f[5]); w0.w = pack2(f[6], f[7]);
                const int lg0 = c0 >> 3, sw = px & 7;
                *(uint4*)&sm.p1.Bs[px * 64 + ((lg0 ^ sw) * 8)] = w0;
            }
        }
        __syncthreads();

        #pragma unroll
        for (int ks = 0; ks < 2; ++ks) {
            bf16x8 af[5], bf[3];
            #pragma unroll
            for (int i = 0; i < 5; ++i)
                af[i] = *(const bf16x8*)&sm.p1.As[((wm * 5 + i) * 16 + m16) * 72
                                                   + ks * 32 + quad * 8];
            #pragma unroll
            for (int n = 0; n < 3; ++n) {
                int px = wn * 48 + n * 16 + m16;
                int lg = ks * 4 + quad;
                bf[n] = *(const bf16x8*)&sm.p1.Bs[px * 64 + ((lg ^ (px & 7)) * 8)];
            }
            #pragma unroll
            for (int i = 0; i < 5; ++i)
                #pragma unroll
                for (int n = 0; n < 3; ++n)
                    acc[i][n] = __builtin_amdgcn_mfma_f32_16x16x32_bf16(
                        af[i], bf[n], acc[i][n], 0, 0, 0);
        }
    }
    __syncthreads();   // phase-1 LDS dead; union flips to phase-2 layout

    // ================= epilogue: acc -> qL / kL / vL =================
    #pragma unroll
    for (int i = 0; i < 5; ++i) {
        const int ob = wm * 80 + i * 16;
        #pragma unroll
        for (int r = 0; r < 4; ++r) {
            const int m = ob + quad * 4 + r;   // out-channel 0..319
            const float bias = bb[m];
            #pragma unroll
            for (int n = 0; n < 3; ++n) {
                int px = wn * 48 + n * 16 + m16;   // 0..191
                int ri = px >> 6, ww = px & 63;
                float val = acc[i][n][r] + bias;
                if (m < CR) {
                    if (ri == 1) sm.p2.qL[ww][m] = val;
                } else if (m < 2 * CR) {
                    sm.p2.kL[ri][ww][m - CR] = val;   // OOB rows masked at use
                } else {
                    bool rv = (unsigned)(h + ri - 1) < (unsigned)HIMG;
                    sm.p2.vL[ri][m - 2 * CR][4 + ww] =
                        rv ? f2bf(val) : (unsigned short)0;
                }
            }
        }
    }
    // zero the 4-px pads on both ends of every vL row (768 rows, 1 pass)
    if (t < 768) {
        int r = t >> 8, c = t & 255;
        *(ushort4*)&sm.p2.vL[r][c][0]  = make_ushort4(0, 0, 0, 0);
        *(ushort4*)&sm.p2.vL[r][c][68] = make_ushort4(0, 0, 0, 0);
    }
    __syncthreads();

    // ---- residual-x prefetch: overlaps HBM latency with energies/softmax ----
    const int px0 = (t & 15) * 4;
    const int cl  = (t >> 4) & 31;
    const int chalf = t >> 9;                 // 0 or 1
    float4 xa_pre[4];
    size_t xbase[4];
    #pragma unroll
    for (int ci = 0; ci < 4; ++ci) {
        int c = cl + 32 * (ci + 4 * chalf);
        xbase[ci] = ((size_t)b * CC + c) * HW + h * WIMG + px0;
        xa_pre[ci] = *(const float4*)&x[xbase[ci]];
    }

    // ================= energies =================
    if (t < 576) {
        int px = t / 9, kk = t - px * 9;
        int di = kk / 3, dj = kk - di * 3;
        int hh = h + di - 1, ww = px + dj - 1;
        float e = 0.f;
        if (hh >= 0 && hh < HIMG && ww >= 0 && ww < WIMG) {
            float s = 0.f;
            #pragma unroll
            for (int c = 0; c < CR; ++c)
                s = fmaf(sm.p2.qL[px][c], sm.p2.kL[di][ww][c], s);
            e = s;
        }
        sm.p2.es[px][kk] = e;
    }
    __syncthreads();

    // ================= softmax =================
    if (t < 64) {
        float m = sm.p2.es[t][0];
        #pragma unroll
        for (int kk = 1; kk < 9; ++kk) m = fmaxf(m, sm.p2.es[t][kk]);
        float ex[9]; float ssum = 0.f;
        #pragma unroll
        for (int kk = 0; kk < 9; ++kk) {
            ex[kk] = __expf(sm.p2.es[t][kk] - m);
            ssum += ex[kk];
        }
        float inv = 1.f / ssum;
        #pragma unroll
        for (int kk = 0; kk < 9; ++kk) sm.p2.aws[t][kk] = ex[kk] * inv;
    }
    __syncthreads();

    // ================= apply + residual =================
    {
        const float g = gamma[0];
        float w[4][9];
        #pragma unroll
        for (int i = 0; i < 4; ++i)
            #pragma unroll
            for (int kk = 0; kk < 9; ++kk) w[i][kk] = sm.p2.aws[px0 + i][kk];

        #pragma unroll
        for (int ci = 0; ci < 4; ++ci) {
            int c = cl + 32 * (ci + 4 * chalf);
            float a0 = 0.f, a1 = 0.f, a2 = 0.f, a3 = 0.f;
            #pragma unroll
            for (int r = 0; r < 3; ++r) {
                const unsigned short* row = &sm.p2.vL[r][c][0];
                ushort4 uc = *(const ushort4*)&row[4 + px0];
                float c0 = bf2f(uc.x), c1 = bf2f(uc.y);
                float c2 = bf2f(uc.z), c3 = bf2f(uc.w);
                float lft = bf2f(row[3 + px0]);
                float rgt = bf2f(row[8 + px0]);
                int r3 = r * 3;
                a0 = fmaf(w[0][r3], lft, fmaf(w[0][r3+1], c0, fmaf(w[0][r3+2], c1, a0)));
                a1 = fmaf(w[1][r3], c0,  fmaf(w[1][r3+1], c1, fmaf(w[1][r3+2], c2, a1)));
                a2 = fmaf(w[2][r3], c1,  fmaf(w[2][r3+1], c2, fmaf(w[2][r3+2], c3, a2)));
                a3 = fmaf(w[3][r3], c2,  fmaf(w[3][r3+1], c3, fmaf(w[3][r3+2], rgt, a3)));
            }
            float4 xa = xa_pre[ci];
            float4 o;
            o.x = fmaf(g, a0, xa.x); o.y = fmaf(g, a1, xa.y);
            o.z = fmaf(g, a2, xa.z); o.w = fmaf(g, a3, xa.w);
            *(float4*)&out[xbase[ci]] = o;
        }
    }
}

extern "C" void kernel_launch(void* const* d_in, const int* in_sizes, int n_in,
                              void* d_out, int out_size, void* d_ws, size_t ws_size,
                              hipStream_t stream)
{
    const float* x     = (const float*)d_in[0];
    const float* Wq    = (const float*)d_in[1];
    const float* bq    = (const float*)d_in[2];
    const float* Wk    = (const float*)d_in[3];
    const float* bk    = (const float*)d_in[4];
    const float* Wv    = (const float*)d_in[5];
    const float* bv    = (const float*)d_in[6];
    const float* gamma = (const float*)d_in[7];
    float* out = (float*)d_out;

    unsigned short* Wb = (unsigned short*)d_ws;        // 160 KB
    float* bb = (float*)(Wb + 320 * CC);               // 1.25 KB

    wconv<<<dim3(320), 256, 0, stream>>>(Wq, bq, Wk, bk, Wv, bv, Wb, bb);
    fused<<<dim3(HIMG, B_), 1024, 0, stream>>>(Wb, bb, x, gamma, out);
}

// Round 5
// 131.721 us; speedup vs baseline: 1.4816x; 1.4182x over previous
//
#include <hip/hip_runtime.h>

#define HW   4096
#define HIMG 64
#define WIMG 64
#define CC   256
#define CR   32
#define B_   8

typedef __attribute__((ext_vector_type(8))) short bf16x8;
typedef __attribute__((ext_vector_type(4))) float f32x4;

__device__ inline unsigned short f2bf(float f) {
    union { float f; unsigned u; } v; v.f = f;
    return (unsigned short)((v.u + 0x8000u) >> 16);
}
__device__ inline float bf2f(unsigned short h) {
    union { unsigned u; float f; } v; v.u = ((unsigned)h) << 16; return v.f;
}
__device__ inline unsigned pack2(float a, float b) {
    return (unsigned)f2bf(a) | ((unsigned)f2bf(b) << 16);
}

// ---------------------------------------------------------------------------
// K1: weights -> bf16, concat [Wq;Wk;Wv] into Wb[320][256]; biases into bb.
// ---------------------------------------------------------------------------
__global__ __launch_bounds__(256) void wconv(
    const float* __restrict__ Wq, const float* __restrict__ bq,
    const float* __restrict__ Wk, const float* __restrict__ bk,
    const float* __restrict__ Wv, const float* __restrict__ bv,
    unsigned short* __restrict__ Wb, float* __restrict__ bb)
{
    const int o = blockIdx.x;   // 0..319
    const float* src; const float* bsrc; int orel;
    if (o < 32)      { src = Wq; bsrc = bq; orel = o;      }
    else if (o < 64) { src = Wk; bsrc = bk; orel = o - 32; }
    else             { src = Wv; bsrc = bv; orel = o - 64; }
    Wb[o * CC + threadIdx.x] = f2bf(src[orel * CC + threadIdx.x]);
    if (threadIdx.x == 0) bb[o] = bsrc[orel];
}

// ---------------------------------------------------------------------------
// K2: fused transpose+convert+GEMM.  (byte-identical to the 134.7µs R0 best)
// ---------------------------------------------------------------------------
__global__ __launch_bounds__(256) void proj_gemm(
    const unsigned short* __restrict__ Wb, const float* __restrict__ bb,
    const float* __restrict__ x,
    float* __restrict__ q, float* __restrict__ k,
    unsigned short* __restrict__ vv)
{
    __shared__ unsigned short As[320 * 72];
    __shared__ float          xt32[64 * 65];
    __shared__ unsigned short Bs[64 * 64];

    const int b   = blockIdx.y;
    const int hw0 = blockIdx.x * 64;
    const int t    = threadIdx.x;
    const int lane = t & 63, wv = t >> 6;
    const int m16  = lane & 15, quad = lane >> 4;

    f32x4 acc[5][4];
    #pragma unroll
    for (int i = 0; i < 5; ++i)
        #pragma unroll
        for (int n = 0; n < 4; ++n)
            acc[i][n] = (f32x4){0.f, 0.f, 0.f, 0.f};

    for (int kc = 0; kc < 4; ++kc) {
        const int k0 = kc * 64;
        if (kc) __syncthreads();            // protect As/xt32/Bs reuse

        // stage A: 320 rows x 64 k bf16 (L2-resident W)
        #pragma unroll
        for (int i = 0; i < 10; ++i) {
            int idx = t + 256 * i;          // 0..2559
            int row = idx >> 3, s8 = idx & 7;
            *(uint4*)&As[row * 72 + s8 * 8] =
                *(const uint4*)&Wb[row * CC + k0 + s8 * 8];
        }
        // stage x chunk fp32: 64 c x 64 px, coalesced along px
        #pragma unroll
        for (int i = 0; i < 4; ++i) {
            int idx = t + 256 * i;          // 0..1023
            int c = idx >> 4, p4 = (idx & 15) * 4;
            float4 vx = *(const float4*)&x[((size_t)b * CC + k0 + c) * HW + hw0 + p4];
            *(float4*)&xt32[c * 65 + p4] = vx;
        }
        __syncthreads();

        // transpose+convert into Bs: thread -> px = lane, 16 channels
        {
            const int px = lane;
            const int c0 = wv * 16;
            float f[16];
            #pragma unroll
            for (int j = 0; j < 16; ++j)
                f[j] = xt32[(c0 + j) * 65 + px];   // bank (c0+j+px)%32: 2-way
            uint4 w0, w1;
            w0.x = pack2(f[0],  f[1]);  w0.y = pack2(f[2],  f[3]);
            w0.z = pack2(f[4],  f[5]);  w0.w = pack2(f[6],  f[7]);
            w1.x = pack2(f[8],  f[9]);  w1.y = pack2(f[10], f[11]);
            w1.z = pack2(f[12], f[13]); w1.w = pack2(f[14], f[15]);
            const int lg0 = c0 >> 3, sw = px & 7;
            *(uint4*)&Bs[px * 64 + ((lg0     ^ sw) * 8)] = w0;
            *(uint4*)&Bs[px * 64 + (((lg0+1) ^ sw) * 8)] = w1;
        }
        __syncthreads();

        #pragma unroll
        for (int ks = 0; ks < 2; ++ks) {
            bf16x8 af[5], bf[4];
            #pragma unroll
            for (int i = 0; i < 5; ++i)
                af[i] = *(const bf16x8*)&As[((wv * 5 + i) * 16 + m16) * 72
                                            + ks * 32 + quad * 8];
            #pragma unroll
            for (int n = 0; n < 4; ++n) {
                int px = n * 16 + m16;
                int lg = ks * 4 + quad;
                bf[n] = *(const bf16x8*)&Bs[px * 64 + ((lg ^ (px & 7)) * 8)];
            }
            #pragma unroll
            for (int i = 0; i < 5; ++i)
                #pragma unroll
                for (int n = 0; n < 4; ++n)
                    acc[i][n] = __builtin_amdgcn_mfma_f32_16x16x32_bf16(
                        af[i], bf[n], acc[i][n], 0, 0, 0);
        }
    }

    // epilogue: D row = quad*4+reg, col = lane&15
    #pragma unroll
    for (int i = 0; i < 5; ++i) {
        const int ob = (wv * 5 + i) * 16;        // 0..304, wave-uniform
        #pragma unroll
        for (int r = 0; r < 4; ++r) {
            const int orow = quad * 4 + r;
            const float bias = bb[ob + orow];
            if (ob < 64) {                        // q or k, fp32
                float* dst = (ob < 32) ? q : k;
                int orel = (ob < 32) ? ob : ob - 32;
                size_t rowbase = ((size_t)b * CR + orel + orow) * HW;
                #pragma unroll
                for (int n = 0; n < 4; ++n)
                    dst[rowbase + hw0 + n * 16 + m16] = acc[i][n][r] + bias;
            } else {                              // v, bf16
                size_t rowbase = ((size_t)b * CC + (ob - 64) + orow) * HW;
                #pragma unroll
                for (int n = 0; n < 4; ++n)
                    vv[rowbase + hw0 + n * 16 + m16] = f2bf(acc[i][n][r] + bias);
            }
        }
    }
}

// ---------------------------------------------------------------------------
// K3: energies + softmax -> aw[b][hw][12]   (byte-identical to R0 best)
// ---------------------------------------------------------------------------
__global__ __launch_bounds__(256) void attn_w(
    const float* __restrict__ q_, const float* __restrict__ k_,
    float* __restrict__ aw)
{
    __shared__ float qs[64][33];
    __shared__ float ks[3][64][33];
    __shared__ float es[64][9];
    const int h = blockIdx.x, b = blockIdx.y, t = threadIdx.x;

    #pragma unroll
    for (int i = 0; i < 2; ++i) {
        int idx = t + 256 * i, cr = idx >> 4, p4 = (idx & 15) * 4;
        float4 vq = *(const float4*)&q_[((size_t)b * CR + cr) * HW + h * WIMG + p4];
        qs[p4 + 0][cr] = vq.x; qs[p4 + 1][cr] = vq.y;
        qs[p4 + 2][cr] = vq.z; qs[p4 + 3][cr] = vq.w;
    }
    #pragma unroll
    for (int r = 0; r < 3; ++r) {
        int hh = h + r - 1;
        bool ok = (hh >= 0) && (hh < HIMG);
        #pragma unroll
        for (int i = 0; i < 2; ++i) {
            int idx = t + 256 * i, cr = idx >> 4, p4 = (idx & 15) * 4;
            float4 vk = make_float4(0.f, 0.f, 0.f, 0.f);
            if (ok)
                vk = *(const float4*)&k_[((size_t)b * CR + cr) * HW + hh * WIMG + p4];
            ks[r][p4 + 0][cr] = vk.x; ks[r][p4 + 1][cr] = vk.y;
            ks[r][p4 + 2][cr] = vk.z; ks[r][p4 + 3][cr] = vk.w;
        }
    }
    __syncthreads();

    for (int id = t; id < 576; id += 256) {
        int px = id / 9, kk = id - px * 9;
        int di = kk / 3, dj = kk - di * 3;
        int hh = h + di - 1, ww = px + dj - 1;
        float e = 0.f;
        if (hh >= 0 && hh < HIMG && ww >= 0 && ww < WIMG) {
            float s = 0.f;
            #pragma unroll
            for (int c = 0; c < CR; ++c) s = fmaf(qs[px][c], ks[di][ww][c], s);
            e = s;
        }
        es[px][kk] = e;
    }
    __syncthreads();

    if (t < 64) {
        float m = es[t][0];
        #pragma unroll
        for (int kk = 1; kk < 9; ++kk) m = fmaxf(m, es[t][kk]);
        float ex[9]; float ssum = 0.f;
        #pragma unroll
        for (int kk = 0; kk < 9; ++kk) { ex[kk] = __expf(es[t][kk] - m); ssum += ex[kk]; }
        float inv = 1.f / ssum;
        float* dst = &aw[((size_t)b * HW + h * WIMG + t) * 12];
        #pragma unroll
        for (int kk = 0; kk < 9; ++kk) dst[kk] = ex[kk] * inv;
    }
}

// ---------------------------------------------------------------------------
// K4: apply weights to v (bf16) + residual.
// CHANGED vs R0 (single variable this round): LDS bank-conflict hygiene.
//  - vs stride 72 -> 73 dwords (odd): the old stride was ≡8 (mod 32), so a
//    wave's accesses collided 8-way on (2c+i) mod 8 with distinct addresses.
//    Odd stride puts the 4 c-groups of a wave in disjoint mod-4 bank classes
//    (2-way within group = free).
//  - aws stride 12 -> 13: stride 12 put 16 distinct addresses on 2 banks
//    (8-way x 36 reads/thread).
//  - Odd strides break float4 alignment -> all vs/aws LDS traffic is scalar
//    (b32), which is conflict-free by the analysis above.
// Global access patterns and all arithmetic identical to R0.
// ---------------------------------------------------------------------------
__global__ __launch_bounds__(256) void apply(
    const float* __restrict__ x, const unsigned short* __restrict__ vv,
    const float* __restrict__ aw, const float* __restrict__ gamma,
    float* __restrict__ out)
{
    __shared__ float vs[3][32][73];   // [row][ch][4 zero | 64 px | 4 zero | 1 pad]
    __shared__ float aws[64][13];
    const int h = blockIdx.x, cb = blockIdx.y, b = blockIdx.z, t = threadIdx.x;

    // stage aws: 768 contiguous global floats, scalar LDS writes (stride 13)
    for (int p = t; p < 768; p += 256) {
        int px = p / 12, kk = p - px * 12;
        aws[px][kk] = aw[((size_t)b * HW + h * WIMG) * 12 + p];
    }
    // stage v rows: global ushort4 loads unchanged; LDS writes scalar
    #pragma unroll
    for (int i = 0; i < 6; ++i) {
        int idx = t + 256 * i;          // 0..1535
        int p4 = (idx & 15) * 4, c = (idx >> 4) & 31, r = idx >> 9;
        int hh = h + r - 1;
        float4 val = make_float4(0.f, 0.f, 0.f, 0.f);
        if (hh >= 0 && hh < HIMG) {
            ushort4 u = *(const ushort4*)&vv[((size_t)b * CC + cb * 32 + c) * HW
                                             + hh * WIMG + p4];
            val = make_float4(bf2f(u.x), bf2f(u.y), bf2f(u.z), bf2f(u.w));
        }
        float* dstp = &vs[r][c][4 + p4];
        dstp[0] = val.x; dstp[1] = val.y; dstp[2] = val.z; dstp[3] = val.w;
    }
    if (t < 96) {
        int r = t >> 5, c = t & 31;
        float* row = &vs[r][c][0];
        row[0] = 0.f; row[1] = 0.f; row[2] = 0.f; row[3] = 0.f;
        row[68] = 0.f; row[69] = 0.f; row[70] = 0.f; row[71] = 0.f;
    }
    __syncthreads();

    const int px0 = (t & 15) * 4;
    const int cl  = t >> 4;
    float w[4][9];
    #pragma unroll
    for (int i = 0; i < 4; ++i)
        #pragma unroll
        for (int kk = 0; kk < 9; ++kk) w[i][kk] = aws[px0 + i][kk];
    const float g = gamma[0];

    #pragma unroll
    for (int ci = 0; ci < 2; ++ci) {
        int c = cl + 16 * ci;
        float a0 = 0.f, a1 = 0.f, a2 = 0.f, a3 = 0.f;
        #pragma unroll
        for (int r = 0; r < 3; ++r) {
            const float* row = &vs[r][c][0];
            float lft = row[3 + px0];
            float c0  = row[4 + px0];
            float c1  = row[5 + px0];
            float c2  = row[6 + px0];
            float c3  = row[7 + px0];
            float rgt = row[8 + px0];
            int r3 = r * 3;
            a0 = fmaf(w[0][r3], lft, fmaf(w[0][r3+1], c0, fmaf(w[0][r3+2], c1, a0)));
            a1 = fmaf(w[1][r3], c0,  fmaf(w[1][r3+1], c1, fmaf(w[1][r3+2], c2, a1)));
            a2 = fmaf(w[2][r3], c1,  fmaf(w[2][r3+1], c2, fmaf(w[2][r3+2], c3, a2)));
            a3 = fmaf(w[3][r3], c2,  fmaf(w[3][r3+1], c3, fmaf(w[3][r3+2], rgt, a3)));
        }
        size_t base = ((size_t)b * CC + cb * 32 + c) * HW + h * WIMG + px0;
        float4 xa = *(const float4*)&x[base];
        float4 o;
        o.x = fmaf(g, a0, xa.x); o.y = fmaf(g, a1, xa.y);
        o.z = fmaf(g, a2, xa.z); o.w = fmaf(g, a3, xa.w);
        *(float4*)&out[base] = o;
    }
}

extern "C" void kernel_launch(void* const* d_in, const int* in_sizes, int n_in,
                              void* d_out, int out_size, void* d_ws, size_t ws_size,
                              hipStream_t stream)
{
    const float* x     = (const float*)d_in[0];
    const float* Wq    = (const float*)d_in[1];
    const float* bq    = (const float*)d_in[2];
    const float* Wk    = (const float*)d_in[3];
    const float* bk    = (const float*)d_in[4];
    const float* Wv    = (const float*)d_in[5];
    const float* bv    = (const float*)d_in[6];
    const float* gamma = (const float*)d_in[7];
    float* out = (float*)d_out;

    float* q  = (float*)d_ws;                                  //  4.19 MB
    float* k  = q + (size_t)B_ * CR * HW;                      //  4.19 MB
    unsigned short* vv = (unsigned short*)(k + (size_t)B_ * CR * HW); // 16.78 MB
    float* aw = (float*)(vv + (size_t)B_ * CC * HW);           //  1.57 MB
    unsigned short* Wb = (unsigned short*)(aw + (size_t)B_ * HW * 12); // 160 KB
    float* bb = (float*)(Wb + 320 * CC);

    wconv<<<dim3(320), 256, 0, stream>>>(Wq, bq, Wk, bk, Wv, bv, Wb, bb);
    proj_gemm<<<dim3(HW / 64, B_), 256, 0, stream>>>(Wb, bb, x, q, k, vv);
    attn_w<<<dim3(HIMG, B_), 256, 0, stream>>>(q, k, aw);
    apply<<<dim3(HIMG, CC / 32, B_), 256, 0, stream>>>(x, vv, aw, gamma, out);
}